// Round 12
// baseline (359.777 us; speedup 1.0000x reference)
//
#include <hip/hip_runtime.h>

#define N_NODES 100000
#define N_EDGES 1600000
#define N_GRAPHS 512
#define DIM 128
#define NCLS 10
#define NBKT 782          // buckets of 128 dst nodes: 782*128 = 100096 >= N
#define BCAP 2560         // padded bucket region (mean 2048, sigma~45 -> 11 sigma slack)

typedef __attribute__((ext_vector_type(8))) short short8;
typedef __attribute__((ext_vector_type(4))) float f32x4;

static __device__ __forceinline__ unsigned short f2bf(float f) {
    unsigned u = __float_as_uint(f);
    unsigned r = (u + 0x7FFF + ((u >> 16) & 1)) >> 16;  // RNE
    return (unsigned short)r;
}
static __device__ __forceinline__ float bf2f(unsigned u) {
    return __uint_as_float(u << 16);
}

// ---------------- W fragment prep + bcnt zero (one launch; R8 proven) ----------------
// blocks 0..63: W1; 64..127: W2; 128..131: zero bcnt.
// wfrag[hi: t<16384][lo: +16384], t = ((kit*8+nt)*64+lane)*8+j
// B element: k = kit*32 + (lane>>4)*8 + j, n = nt*16 + (lane&15)

__global__ void k_wprep(const float* __restrict__ W1, const float* __restrict__ W2,
                        unsigned short* __restrict__ wf1, unsigned short* __restrict__ wf2,
                        int* __restrict__ bcnt) {
    int b = blockIdx.x;
    if (b >= 128) {
        int i = (b - 128) * 256 + threadIdx.x;
        if (i < NBKT) bcnt[i] = 0;
        return;
    }
    const float* W = (b < 64) ? W1 : W2;
    unsigned short* wfrag = (b < 64) ? wf1 : wf2;
    int t = (b & 63) * 256 + threadIdx.x;   // 0..16383
    int j = t & 7, lane = (t >> 3) & 63, nt = (t >> 9) & 7, kit = t >> 12;
    int k = kit * 32 + (lane >> 4) * 8 + j;
    int n = nt * 16 + (lane & 15);
    float v = W[k * 128 + n];
    unsigned short h = f2bf(v);
    wfrag[t] = h;
    wfrag[16384 + t] = f2bf(v - bf2f(h));
}

// ---------------- edge prep phase A: padded bucketing, 1024 threads (R11 proven) ----------------

__global__ __launch_bounds__(1024) void k_bucket(
    const int* __restrict__ src, const int* __restrict__ dst,
    int* __restrict__ bcnt, unsigned* __restrict__ bpack, int E) {
    __shared__ int cnt[NBKT];
    __shared__ int base[NBKT];
    int tid = threadIdx.x;
    for (int i = tid; i < NBKT; i += 1024) cnt[i] = 0;
    __syncthreads();
    int e0 = blockIdx.x * 4096 + tid;
    unsigned pk[4]; short bk[4];
#pragma unroll
    for (int j = 0; j < 4; j++) {
        int e = e0 + j * 1024;
        if (e < E) {
            int s = src[e], d = dst[e];
            bk[j] = (short)(d >> 7);
            pk[j] = ((unsigned)(d & 127) << 17) | (unsigned)s;
            atomicAdd(&cnt[bk[j]], 1);
        } else bk[j] = -1;
    }
    __syncthreads();
    for (int i = tid; i < NBKT; i += 1024) {
        int c = cnt[i];
        base[i] = c ? atomicAdd(&bcnt[i], c) : 0;
        cnt[i] = 0;
    }
    __syncthreads();
#pragma unroll
    for (int j = 0; j < 4; j++) {
        if (bk[j] >= 0) {
            int p = base[bk[j]] + atomicAdd(&cnt[bk[j]], 1);
            if (p < BCAP) bpack[(size_t)bk[j] * BCAP + p] = pk[j];
        }
    }
}

// ---------------- fused bsort + gemm1 bodies (same node slab per block) ----------------

static __device__ __forceinline__ void bsort_body(
    char* smemraw, int b,
    const unsigned* __restrict__ bpack, const int* __restrict__ bcnt,
    int* __restrict__ rp, float* __restrict__ dinv,
    int* __restrict__ esrc, int N, float* __restrict__ dvs) {
    int* lds      = (int*)smemraw;       // [256]
    int* cnt      = lds + 256;           // [128]
    int* scan     = lds + 384;           // [128]
    int* cur      = lds + 512;           // [128]
    int* gbase_sh = lds + 640;           // [1]
    int tid = threadIdx.x;
    int v[4], pre[4];
    int s = 0;
#pragma unroll
    for (int j = 0; j < 4; j++) {
        int idx = tid * 4 + j;
        v[j] = (idx < NBKT) ? min(bcnt[idx], BCAP) : 0;
        pre[j] = s; s += v[j];
    }
    lds[tid] = s;
    __syncthreads();
    for (int off = 1; off < 256; off <<= 1) {
        int t = (tid >= off) ? lds[tid - off] : 0;
        __syncthreads();
        lds[tid] += t;
        __syncthreads();
    }
    if (tid == (b >> 2)) *gbase_sh = lds[tid] - s + pre[b & 3];
    if (tid < 128) cnt[tid] = 0;
    __syncthreads();
    int gbase = *gbase_sh;
    int n0 = b << 7;
    int m = min(bcnt[b], BCAP);
    const unsigned* bp = bpack + (size_t)b * BCAP;
    for (int j = tid; j < m; j += 256) atomicAdd(&cnt[bp[j] >> 17], 1);
    __syncthreads();
    if (tid < 128) scan[tid] = cnt[tid];
    __syncthreads();
    for (int off = 1; off < 128; off <<= 1) {
        int t = (tid < 128 && tid >= off) ? scan[tid - off] : 0;
        __syncthreads();
        if (tid < 128) scan[tid] += t;
        __syncthreads();
    }
    if (tid < 128) {
        int c = cnt[tid];
        int excl = scan[tid] - c;
        int node = n0 + tid;
        float dv = rsqrtf((float)(c + 1));          // +1 self loop
        if (node <= N) rp[node] = gbase + excl;
        if (node < N) dinv[node] = dv;
        dvs[tid] = dv;                              // LDS stash for gemm phase
        cur[tid] = gbase + excl;
    }
    __syncthreads();
    for (int j = tid; j < m; j += 256) {
        unsigned pk = bp[j];
        int p = atomicAdd(&cur[pk >> 17], 1);
        esrc[p] = (int)(pk & 0x1FFFF);
    }
}

// MFMA GEMM (fp32 A): ybf = bf16(dvs * (A @ W)), dvs from LDS (this block's slab).
static __device__ __forceinline__ void gemm_f32_body(
    char* smemraw, int rowBlk,
    const float* __restrict__ A, const unsigned short* __restrict__ wfrag,
    const float* __restrict__ dvs, unsigned short* __restrict__ ybf, int M) {
    unsigned short* ldsw = (unsigned short*)smemraw;   // 4*32*136 shorts
    int tid = threadIdx.x, wave = tid >> 6, lane = tid & 63;
    int m = lane & 15, quad = lane >> 4;
    int rowBase = rowBlk * 128 + wave * 32;
    int r0 = rowBase + m, r1 = rowBase + 16 + m;
    for (int i = tid; i < 2048; i += 256)
        ((short8*)ldsw)[i] = ((const short8*)wfrag)[i];   // stage W-hi
    __syncthreads();
    f32x4 acc0[8], acc1[8];
#pragma unroll
    for (int i = 0; i < 8; i++) { acc0[i] = (f32x4){0,0,0,0}; acc1[i] = (f32x4){0,0,0,0}; }
    const unsigned short* wlo = wfrag + 16384;

#pragma unroll
    for (int kit = 0; kit < 4; kit++) {
        float a0[8], a1[8];
        if (r0 < M) {
            const float4* ap = (const float4*)(A + (size_t)r0 * 128 + kit * 32 + quad * 8);
            float4 f0 = ap[0], f1 = ap[1];
            a0[0]=f0.x; a0[1]=f0.y; a0[2]=f0.z; a0[3]=f0.w; a0[4]=f1.x; a0[5]=f1.y; a0[6]=f1.z; a0[7]=f1.w;
        } else { for (int j = 0; j < 8; j++) a0[j] = 0.f; }
        if (r1 < M) {
            const float4* ap = (const float4*)(A + (size_t)r1 * 128 + kit * 32 + quad * 8);
            float4 f0 = ap[0], f1 = ap[1];
            a1[0]=f0.x; a1[1]=f0.y; a1[2]=f0.z; a1[3]=f0.w; a1[4]=f1.x; a1[5]=f1.y; a1[6]=f1.z; a1[7]=f1.w;
        } else { for (int j = 0; j < 8; j++) a1[j] = 0.f; }
        short8 ahi0, alo0, ahi1, alo1;
#pragma unroll
        for (int j = 0; j < 8; j++) {
            unsigned short h0 = f2bf(a0[j]);
            ahi0[j] = (short)h0; alo0[j] = (short)f2bf(a0[j] - bf2f(h0));
            unsigned short h1 = f2bf(a1[j]);
            ahi1[j] = (short)h1; alo1[j] = (short)f2bf(a1[j] - bf2f(h1));
        }
        int fb = kit * 4096 + lane * 8;
#pragma unroll
        for (int nt = 0; nt < 8; nt++) {
            int idx = fb + nt * 512;
            short8 bhi = *(const short8*)(ldsw + idx);
            short8 blo = *(const short8*)(wlo + idx);
            acc0[nt] = __builtin_amdgcn_mfma_f32_16x16x32_bf16(ahi0, bhi, acc0[nt], 0, 0, 0);
            acc0[nt] = __builtin_amdgcn_mfma_f32_16x16x32_bf16(alo0, bhi, acc0[nt], 0, 0, 0);
            acc0[nt] = __builtin_amdgcn_mfma_f32_16x16x32_bf16(ahi0, blo, acc0[nt], 0, 0, 0);
            acc1[nt] = __builtin_amdgcn_mfma_f32_16x16x32_bf16(ahi1, bhi, acc1[nt], 0, 0, 0);
            acc1[nt] = __builtin_amdgcn_mfma_f32_16x16x32_bf16(alo1, bhi, acc1[nt], 0, 0, 0);
            acc1[nt] = __builtin_amdgcn_mfma_f32_16x16x32_bf16(ahi1, blo, acc1[nt], 0, 0, 0);
        }
    }
    __syncthreads();   // all waves done reading W-hi before scratch reuse
    unsigned short* wsm = ldsw + wave * 32 * 136;
#pragma unroll
    for (int rg = 0; rg < 4; rg++) {
        float s0 = dvs[wave * 32 + quad * 4 + rg];
        float s1 = dvs[wave * 32 + 16 + quad * 4 + rg];
#pragma unroll
        for (int nt = 0; nt < 8; nt++) {
            wsm[(quad * 4 + rg) * 136 + nt * 16 + m] = f2bf(acc0[nt][rg] * s0);
            wsm[(16 + quad * 4 + rg) * 136 + nt * 16 + m] = f2bf(acc1[nt][rg] * s1);
        }
    }
    __syncthreads();
#pragma unroll
    for (int i = 0; i < 8; i++) {
        int rl = i * 4 + quad;
        int grow = rowBase + rl;
        if (grow < M) {
            short8 v = *(const short8*)(wsm + rl * 136 + m * 8);
            *(short8*)(ybf + (size_t)grow * 128 + m * 8) = v;
        }
    }
}

// ---------------- fused launch: block b = bsort(b) then gemm1(b) ----------------

__global__ __launch_bounds__(256) void k_fuse(
    const unsigned* __restrict__ bpack, const int* __restrict__ bcnt,
    int* __restrict__ rp, float* __restrict__ dinv, int* __restrict__ esrc, int N,
    const float* __restrict__ A, const unsigned short* __restrict__ wfrag,
    unsigned short* __restrict__ ybf, int M) {
    __shared__ __align__(16) char smem[4 * 32 * 136 * 2];
    __shared__ float dvs[128];
    int b = blockIdx.x;
    bsort_body(smem, b, bpack, bcnt, rp, dinv, esrc, N, dvs);
    __syncthreads();
    gemm_f32_body(smem, b, A, wfrag, dvs, ybf, M);
}

// ---------------- fused agg1 + gemm2 (64-node tile) ----------------
// R8 proved the 32-node form (77us). The +13us over the 64us pure-agg floor
// matches W2 L2 traffic: 3125 blocks x 128KB = 400MB / ~34.5TB/s ~= 12us.
// 64-node tile + B-fragment register reuse across 4 row-groups cuts W2 L2
// bytes 4x (100MB total). LDS 17.4KB (still ~8 blocks/CU — no R4 cliff).
// Gather loop byte-identical; per-node MFMA accumulation order unchanged.

__global__ __launch_bounds__(256) void k_aggemm2(
    const unsigned short* __restrict__ y, const float* __restrict__ dinv,
    const int* __restrict__ rp, const int* __restrict__ esrc,
    const float* __restrict__ bias, const unsigned short* __restrict__ wfrag,
    unsigned short* __restrict__ ybf, int N) {
    __shared__ unsigned h1[64 * 68];     // [64 rows][64 u32 + 4 pad] = 17408 B
    int tid = threadIdx.x, wave = tid >> 6, lane = tid & 63;
    int slab = blockIdx.x * 64;
    const unsigned* y2 = (const unsigned*)y;
    float2 bv = ((const float2*)bias)[lane];

    // ---- Phase A: aggregate (proven k_agg inner loop; H1 -> LDS); 16 nodes/wave ----
    for (int ni = 0; ni < 16; ni++) {
        int lr = wave * 16 + ni;
        int node = slab + lr;
        unsigned packed = 0;
        if (node < N) {
            unsigned vs = y2[(size_t)node * 64 + lane];       // self loop
            float a0 = bf2f(vs & 0xFFFF), a1 = bf2f(vs >> 16);
            int beg = rp[node], end = rp[node + 1];
            int j = beg;
            while (j < end) {
                int idxv = (j + lane < end) ? esrc[j + lane] : 0;
                int cnt = end - j; if (cnt > 64) cnt = 64;
                int i = 0;
                for (; i + 4 <= cnt; i += 4) {
                    int s0 = __shfl(idxv, i + 0);
                    int s1 = __shfl(idxv, i + 1);
                    int s2 = __shfl(idxv, i + 2);
                    int s3 = __shfl(idxv, i + 3);
                    unsigned v0 = y2[(size_t)s0 * 64 + lane];
                    unsigned v1 = y2[(size_t)s1 * 64 + lane];
                    unsigned v2 = y2[(size_t)s2 * 64 + lane];
                    unsigned v3 = y2[(size_t)s3 * 64 + lane];
                    a0 += bf2f(v0 & 0xFFFF); a1 += bf2f(v0 >> 16);
                    a0 += bf2f(v1 & 0xFFFF); a1 += bf2f(v1 >> 16);
                    a0 += bf2f(v2 & 0xFFFF); a1 += bf2f(v2 >> 16);
                    a0 += bf2f(v3 & 0xFFFF); a1 += bf2f(v3 >> 16);
                }
                for (; i < cnt; i++) {
                    int s = __shfl(idxv, i);
                    unsigned v = y2[(size_t)s * 64 + lane];
                    a0 += bf2f(v & 0xFFFF); a1 += bf2f(v >> 16);
                }
                j += cnt;
            }
            float s = dinv[node];
            float o0 = fmaxf(s * a0 + bv.x, 0.f);             // relu (conv1)
            float o1 = fmaxf(s * a1 + bv.y, 0.f);
            packed = (unsigned)f2bf(o0) | ((unsigned)f2bf(o1) << 16);
        }
        h1[lr * 68 + lane] = packed;
    }
    __syncthreads();

    // ---- Phase B: gemm2 64x128 tile; wave w -> col tiles {2w,2w+1}, 4 row-groups ----
    const unsigned short* h1us = (const unsigned short*)h1;   // row stride 136 ushort
    int m = lane & 15, quad = lane >> 4;
    f32x4 acc[4][2];
#pragma unroll
    for (int rt = 0; rt < 4; rt++)
#pragma unroll
        for (int ct = 0; ct < 2; ct++) acc[rt][ct] = (f32x4){0,0,0,0};
    const unsigned short* wlo = wfrag + 16384;
#pragma unroll
    for (int kit = 0; kit < 4; kit++) {
        short8 ah[4];
#pragma unroll
        for (int rt = 0; rt < 4; rt++)
            ah[rt] = *(const short8*)(h1us + (rt * 16 + m) * 136 + kit * 32 + quad * 8);
#pragma unroll
        for (int ct = 0; ct < 2; ct++) {
            int idx = kit * 4096 + lane * 8 + (wave * 2 + ct) * 512;
            short8 bhi = *(const short8*)(wfrag + idx);   // L2-hot; reused 4x from regs
            short8 blo = *(const short8*)(wlo + idx);
#pragma unroll
            for (int rt = 0; rt < 4; rt++) {
                acc[rt][ct] = __builtin_amdgcn_mfma_f32_16x16x32_bf16(ah[rt], bhi, acc[rt][ct], 0, 0, 0);
                acc[rt][ct] = __builtin_amdgcn_mfma_f32_16x16x32_bf16(ah[rt], blo, acc[rt][ct], 0, 0, 0);
            }
        }
    }
    float dvv[4];
#pragma unroll
    for (int rt = 0; rt < 4; rt++) {
        int r = slab + rt * 16 + m;
        dvv[rt] = (r < N) ? dinv[r] : 0.f;
    }
    __syncthreads();   // ALL waves done reading h1 before scratch reuse
    unsigned short* wsm = (unsigned short*)h1;
#pragma unroll
    for (int rt = 0; rt < 4; rt++) {
#pragma unroll
        for (int rg = 0; rg < 4; rg++) {
            float s0 = __shfl(dvv[rt], quad * 4 + rg);
#pragma unroll
            for (int ct = 0; ct < 2; ct++) {
                int colb = (wave * 2 + ct) * 16 + m;
                wsm[(rt * 16 + quad * 4 + rg) * 136 + colb] = f2bf(acc[rt][ct][rg] * s0);
            }
        }
    }
    __syncthreads();
#pragma unroll
    for (int pass = 0; pass < 4; pass++) {
        int flat = pass * 256 + tid;
        int rl = flat >> 4, c8 = flat & 15;
        int grow = slab + rl;
        if (grow < N) {
            short8 v = *(const short8*)(wsm + rl * 136 + c8 * 8);
            *(short8*)(ybf + (size_t)grow * 128 + c8 * 8) = v;
        }
    }
}

// ---------------- CSR aggregation (PROVEN R0/R3 form, row-major) ----------------

__global__ __launch_bounds__(256) void k_agg(
    const unsigned short* __restrict__ y, const float* __restrict__ dinv,
    const int* __restrict__ rp, const int* __restrict__ esrc,
    const float* __restrict__ bias, unsigned* __restrict__ out, int relu, int N) {
    int wave = threadIdx.x >> 6;
    int lane = threadIdx.x & 63;
    int node = blockIdx.x * 4 + wave;
    if (node >= N) return;
    const unsigned* y2 = (const unsigned*)y;   // 2 bf16 per u32, row stride 64
    unsigned vs = y2[(size_t)node * 64 + lane];       // self loop
    float a0 = bf2f(vs & 0xFFFF), a1 = bf2f(vs >> 16);
    int beg = rp[node], end = rp[node + 1];
    int j = beg;
    while (j < end) {
        int idxv = (j + lane < end) ? esrc[j + lane] : 0;
        int cnt = end - j; if (cnt > 64) cnt = 64;
        int i = 0;
        for (; i + 4 <= cnt; i += 4) {
            int s0 = __shfl(idxv, i + 0);
            int s1 = __shfl(idxv, i + 1);
            int s2 = __shfl(idxv, i + 2);
            int s3 = __shfl(idxv, i + 3);
            unsigned v0 = y2[(size_t)s0 * 64 + lane];
            unsigned v1 = y2[(size_t)s1 * 64 + lane];
            unsigned v2 = y2[(size_t)s2 * 64 + lane];
            unsigned v3 = y2[(size_t)s3 * 64 + lane];
            a0 += bf2f(v0 & 0xFFFF); a1 += bf2f(v0 >> 16);
            a0 += bf2f(v1 & 0xFFFF); a1 += bf2f(v1 >> 16);
            a0 += bf2f(v2 & 0xFFFF); a1 += bf2f(v2 >> 16);
            a0 += bf2f(v3 & 0xFFFF); a1 += bf2f(v3 >> 16);
        }
        for (; i < cnt; i++) {
            int s = __shfl(idxv, i);
            unsigned v = y2[(size_t)s * 64 + lane];
            a0 += bf2f(v & 0xFFFF); a1 += bf2f(v >> 16);
        }
        j += cnt;
    }
    float s = dinv[node];
    float2 bv = ((const float2*)bias)[lane];
    float o0 = s * a0 + bv.x;
    float o1 = s * a1 + bv.y;
    if (relu) { o0 = fmaxf(o0, 0.f); o1 = fmaxf(o1, 0.f); }
    out[(size_t)node * 64 + lane] = (unsigned)f2bf(o0) | ((unsigned)f2bf(o1) << 16);
}

// ---------------- fused mean-pool + classifier head (proven) ----------------

__global__ __launch_bounds__(256) void k_poolhead(
    const unsigned* __restrict__ h2, const int* __restrict__ batch,
    const float* __restrict__ Wc, const float* __restrict__ bc,
    float* __restrict__ out, int n) {
    __shared__ float2 red[4][64];
    __shared__ float grow[DIM];
    int gid = blockIdx.x;
    int tid = threadIdx.x, wave = tid >> 6, lane = tid & 63;
    int lo = 0, hi = n;
    while (lo < hi) { int mid = (lo + hi) >> 1; if (batch[mid] < gid) lo = mid + 1; else hi = mid; }
    int start = lo;
    hi = n;
    while (lo < hi) { int mid = (lo + hi) >> 1; if (batch[mid] < gid + 1) lo = mid + 1; else hi = mid; }
    int end = lo;
    float a0 = 0.f, a1 = 0.f;
    for (int r = start + wave; r < end; r += 4) {
        unsigned v = h2[(size_t)r * 64 + lane];
        a0 += bf2f(v & 0xFFFF); a1 += bf2f(v >> 16);
    }
    red[wave][lane] = make_float2(a0, a1);
    __syncthreads();
    if (tid < 64) {
        float2 s = red[0][tid];
        s.x += red[1][tid].x; s.y += red[1][tid].y;
        s.x += red[2][tid].x; s.y += red[2][tid].y;
        s.x += red[3][tid].x; s.y += red[3][tid].y;
        int cnt = end - start;
        float inv = 1.f / (float)(cnt > 0 ? cnt : 1);
        grow[tid * 2] = s.x * inv;
        grow[tid * 2 + 1] = s.y * inv;
    }
    __syncthreads();
    if (tid < NCLS) {
        float acc = bc[tid];
#pragma unroll 16
        for (int k = 0; k < DIM; k++) acc += grow[k] * Wc[k * NCLS + tid];
        out[gid * NCLS + tid] = acc;
    }
}

extern "C" void kernel_launch(void* const* d_in, const int* in_sizes, int n_in,
                              void* d_out, int out_size, void* d_ws, size_t ws_size,
                              hipStream_t stream) {
    const float* x    = (const float*)d_in[0];
    const int*   ei   = (const int*)d_in[1];
    const int*   batch= (const int*)d_in[2];
    const float* W1   = (const float*)d_in[3];
    const float* b1   = (const float*)d_in[4];
    const float* W2   = (const float*)d_in[5];
    const float* b2   = (const float*)d_in[6];
    const float* Wc   = (const float*)d_in[7];
    const float* bc   = (const float*)d_in[8];
    float* out = (float*)d_out;
    const int N = N_NODES, E = N_EDGES;
    const int* src = ei;
    const int* dst = ei + E;

    char* ws = (char*)d_ws;
    size_t off = 0;
    auto carve = [&](size_t bytes) -> void* {
        void* p = ws + off;
        off = (off + bytes + 255) & ~(size_t)255;
        return p;
    };
    int*      rp    = (int*)     carve((size_t)(N + 1) * 4);
    float*    dinv  = (float*)   carve((size_t)N * 4);
    int*      bcnt  = (int*)     carve(NBKT * 4);
    unsigned* bpack = (unsigned*)carve((size_t)NBKT * BCAP * 4);
    int*      esrc  = (int*)     carve((size_t)E * 4);
    unsigned short* wf1 = (unsigned short*)carve(2 * 16384 * 2);
    unsigned short* wf2 = (unsigned short*)carve(2 * 16384 * 2);
    unsigned short* bufY = (unsigned short*)carve((size_t)N * DIM * 2);
    unsigned short* bufH = (unsigned short*)carve((size_t)N * DIM * 2);
    (void)ws_size; (void)n_in; (void)in_sizes; (void)out_size;

    const int nbBkt = (E + 4095) / 4096;        // 391 bucket blocks

    hipLaunchKernelGGL(k_wprep,  dim3(128 + (NBKT + 255) / 256), dim3(256), 0, stream, W1, W2, wf1, wf2, bcnt);
    hipLaunchKernelGGL(k_bucket, dim3(nbBkt), dim3(1024), 0, stream, src, dst, bcnt, bpack, E);
    // fused: block b does bsort(bucket b) then gemm1(rows of bucket b) -> Y1 (pre-scaled)
    hipLaunchKernelGGL(k_fuse, dim3(NBKT), dim3(256), 0, stream,
                       bpack, bcnt, rp, dinv, esrc, N, x, wf1, bufY, N);
    // fused: agg1 (H1 in 17.4KB LDS, 64-node tile) + gemm2 -> Y2 (pre-scaled)
    hipLaunchKernelGGL(k_aggemm2, dim3((N + 63) / 64), dim3(256), 0, stream,
                       bufY, dinv, rp, esrc, b1, wf2, bufH, N);
    // conv2 aggregate: H2 = dinv*agg(Y2) + b2
    hipLaunchKernelGGL(k_agg, dim3((N + 3) / 4), dim3(256), 0, stream, bufH, dinv, rp, esrc, b2, (unsigned*)bufY, 0, N);
    // fused pool + head
    hipLaunchKernelGGL(k_poolhead, dim3(N_GRAPHS), dim3(256), 0, stream, (const unsigned*)bufY, batch, Wc, bc, out, N);
}

// Round 13
// 320.025 us; speedup vs baseline: 1.1242x; 1.1242x over previous
//
#include <hip/hip_runtime.h>

#define N_NODES 100000
#define N_EDGES 1600000
#define N_GRAPHS 512
#define DIM 128
#define NCLS 10
#define NBKT 782          // buckets of 128 dst nodes: 782*128 = 100096 >= N
#define BCAP 2560         // padded bucket region (mean 2048, sigma~45 -> 11 sigma slack)

typedef __attribute__((ext_vector_type(8))) short short8;
typedef __attribute__((ext_vector_type(4))) float f32x4;

static __device__ __forceinline__ unsigned short f2bf(float f) {
    unsigned u = __float_as_uint(f);
    unsigned r = (u + 0x7FFF + ((u >> 16) & 1)) >> 16;  // RNE
    return (unsigned short)r;
}
static __device__ __forceinline__ float bf2f(unsigned u) {
    return __uint_as_float(u << 16);
}

// ---------------- merged launch 1: W-frag prep (head blocks) + bucketing ----------------
// Blocks 0..31 (HEAD of grid, dispatched first): W1/W2 hi/lo fragment prep —
// tiny, finish fast, bucket blocks fill in behind (R10's TAIL placement
// straggled past bucket's finish; head placement ends at ~bucket-alone time).
// Blocks 32..: bucket 4096 edges each, 1024 threads (R11 proven).
// bcnt pre-zeroed by hipMemsetAsync (stream-ordered, before kernel start).
// wfrag[hi: t<16384][lo: +16384], t = ((kit*8+nt)*64+lane)*8+j
// B element: k = kit*32 + (lane>>4)*8 + j, n = nt*16 + (lane&15)

__global__ __launch_bounds__(1024) void k_bucket(
    const int* __restrict__ src, const int* __restrict__ dst,
    int* __restrict__ bcnt, unsigned* __restrict__ bpack, int E,
    const float* __restrict__ W1, const float* __restrict__ W2,
    unsigned short* __restrict__ wf1, unsigned short* __restrict__ wf2) {
    if ((int)blockIdx.x < 32) {
        int b = blockIdx.x;                 // 0..15: W1, 16..31: W2
        const float* W = (b < 16) ? W1 : W2;
        unsigned short* wfrag = (b < 16) ? wf1 : wf2;
        int t = (b & 15) * 1024 + threadIdx.x;   // 0..16383
        int j = t & 7, lane = (t >> 3) & 63, nt = (t >> 9) & 7, kit = t >> 12;
        int k = kit * 32 + (lane >> 4) * 8 + j;
        int n = nt * 16 + (lane & 15);
        float v = W[k * 128 + n];
        unsigned short h = f2bf(v);
        wfrag[t] = h;
        wfrag[16384 + t] = f2bf(v - bf2f(h));
        return;
    }
    int bid = blockIdx.x - 32;
    __shared__ int cnt[NBKT];
    __shared__ int base[NBKT];
    int tid = threadIdx.x;
    for (int i = tid; i < NBKT; i += 1024) cnt[i] = 0;
    __syncthreads();
    int e0 = bid * 4096 + tid;
    unsigned pk[4]; short bk[4];
#pragma unroll
    for (int j = 0; j < 4; j++) {
        int e = e0 + j * 1024;
        if (e < E) {
            int s = src[e], d = dst[e];
            bk[j] = (short)(d >> 7);
            pk[j] = ((unsigned)(d & 127) << 17) | (unsigned)s;
            atomicAdd(&cnt[bk[j]], 1);
        } else bk[j] = -1;
    }
    __syncthreads();
    for (int i = tid; i < NBKT; i += 1024) {
        int c = cnt[i];
        base[i] = c ? atomicAdd(&bcnt[i], c) : 0;
        cnt[i] = 0;
    }
    __syncthreads();
#pragma unroll
    for (int j = 0; j < 4; j++) {
        if (bk[j] >= 0) {
            int p = base[bk[j]] + atomicAdd(&cnt[bk[j]], 1);
            if (p < BCAP) bpack[(size_t)bk[j] * BCAP + p] = pk[j];
        }
    }
}

// ---------------- fused bsort + gemm1 bodies (same node slab per block) ----------------

static __device__ __forceinline__ void bsort_body(
    char* smemraw, int b,
    const unsigned* __restrict__ bpack, const int* __restrict__ bcnt,
    int* __restrict__ rp, float* __restrict__ dinv,
    int* __restrict__ esrc, int N, float* __restrict__ dvs) {
    int* lds      = (int*)smemraw;       // [256]
    int* cnt      = lds + 256;           // [128]
    int* scan     = lds + 384;           // [128]
    int* cur      = lds + 512;           // [128]
    int* gbase_sh = lds + 640;           // [1]
    int tid = threadIdx.x;
    int v[4], pre[4];
    int s = 0;
#pragma unroll
    for (int j = 0; j < 4; j++) {
        int idx = tid * 4 + j;
        v[j] = (idx < NBKT) ? min(bcnt[idx], BCAP) : 0;
        pre[j] = s; s += v[j];
    }
    lds[tid] = s;
    __syncthreads();
    for (int off = 1; off < 256; off <<= 1) {
        int t = (tid >= off) ? lds[tid - off] : 0;
        __syncthreads();
        lds[tid] += t;
        __syncthreads();
    }
    if (tid == (b >> 2)) *gbase_sh = lds[tid] - s + pre[b & 3];
    if (tid < 128) cnt[tid] = 0;
    __syncthreads();
    int gbase = *gbase_sh;
    int n0 = b << 7;
    int m = min(bcnt[b], BCAP);
    const unsigned* bp = bpack + (size_t)b * BCAP;
    for (int j = tid; j < m; j += 256) atomicAdd(&cnt[bp[j] >> 17], 1);
    __syncthreads();
    if (tid < 128) scan[tid] = cnt[tid];
    __syncthreads();
    for (int off = 1; off < 128; off <<= 1) {
        int t = (tid < 128 && tid >= off) ? scan[tid - off] : 0;
        __syncthreads();
        if (tid < 128) scan[tid] += t;
        __syncthreads();
    }
    if (tid < 128) {
        int c = cnt[tid];
        int excl = scan[tid] - c;
        int node = n0 + tid;
        float dv = rsqrtf((float)(c + 1));          // +1 self loop
        if (node <= N) rp[node] = gbase + excl;
        if (node < N) dinv[node] = dv;
        dvs[tid] = dv;                              // LDS stash for gemm phase
        cur[tid] = gbase + excl;
    }
    __syncthreads();
    for (int j = tid; j < m; j += 256) {
        unsigned pk = bp[j];
        int p = atomicAdd(&cur[pk >> 17], 1);
        esrc[p] = (int)(pk & 0x1FFFF);
    }
}

// MFMA GEMM (fp32 A): ybf = bf16(dvs * (A @ W)), dvs from LDS (this block's slab).
static __device__ __forceinline__ void gemm_f32_body(
    char* smemraw, int rowBlk,
    const float* __restrict__ A, const unsigned short* __restrict__ wfrag,
    const float* __restrict__ dvs, unsigned short* __restrict__ ybf, int M) {
    unsigned short* ldsw = (unsigned short*)smemraw;   // 4*32*136 shorts
    int tid = threadIdx.x, wave = tid >> 6, lane = tid & 63;
    int m = lane & 15, quad = lane >> 4;
    int rowBase = rowBlk * 128 + wave * 32;
    int r0 = rowBase + m, r1 = rowBase + 16 + m;
    for (int i = tid; i < 2048; i += 256)
        ((short8*)ldsw)[i] = ((const short8*)wfrag)[i];   // stage W-hi
    __syncthreads();
    f32x4 acc0[8], acc1[8];
#pragma unroll
    for (int i = 0; i < 8; i++) { acc0[i] = (f32x4){0,0,0,0}; acc1[i] = (f32x4){0,0,0,0}; }
    const unsigned short* wlo = wfrag + 16384;

#pragma unroll
    for (int kit = 0; kit < 4; kit++) {
        float a0[8], a1[8];
        if (r0 < M) {
            const float4* ap = (const float4*)(A + (size_t)r0 * 128 + kit * 32 + quad * 8);
            float4 f0 = ap[0], f1 = ap[1];
            a0[0]=f0.x; a0[1]=f0.y; a0[2]=f0.z; a0[3]=f0.w; a0[4]=f1.x; a0[5]=f1.y; a0[6]=f1.z; a0[7]=f1.w;
        } else { for (int j = 0; j < 8; j++) a0[j] = 0.f; }
        if (r1 < M) {
            const float4* ap = (const float4*)(A + (size_t)r1 * 128 + kit * 32 + quad * 8);
            float4 f0 = ap[0], f1 = ap[1];
            a1[0]=f0.x; a1[1]=f0.y; a1[2]=f0.z; a1[3]=f0.w; a1[4]=f1.x; a1[5]=f1.y; a1[6]=f1.z; a1[7]=f1.w;
        } else { for (int j = 0; j < 8; j++) a1[j] = 0.f; }
        short8 ahi0, alo0, ahi1, alo1;
#pragma unroll
        for (int j = 0; j < 8; j++) {
            unsigned short h0 = f2bf(a0[j]);
            ahi0[j] = (short)h0; alo0[j] = (short)f2bf(a0[j] - bf2f(h0));
            unsigned short h1 = f2bf(a1[j]);
            ahi1[j] = (short)h1; alo1[j] = (short)f2bf(a1[j] - bf2f(h1));
        }
        int fb = kit * 4096 + lane * 8;
#pragma unroll
        for (int nt = 0; nt < 8; nt++) {
            int idx = fb + nt * 512;
            short8 bhi = *(const short8*)(ldsw + idx);
            short8 blo = *(const short8*)(wlo + idx);
            acc0[nt] = __builtin_amdgcn_mfma_f32_16x16x32_bf16(ahi0, bhi, acc0[nt], 0, 0, 0);
            acc0[nt] = __builtin_amdgcn_mfma_f32_16x16x32_bf16(alo0, bhi, acc0[nt], 0, 0, 0);
            acc0[nt] = __builtin_amdgcn_mfma_f32_16x16x32_bf16(ahi0, blo, acc0[nt], 0, 0, 0);
            acc1[nt] = __builtin_amdgcn_mfma_f32_16x16x32_bf16(ahi1, bhi, acc1[nt], 0, 0, 0);
            acc1[nt] = __builtin_amdgcn_mfma_f32_16x16x32_bf16(alo1, bhi, acc1[nt], 0, 0, 0);
            acc1[nt] = __builtin_amdgcn_mfma_f32_16x16x32_bf16(ahi1, blo, acc1[nt], 0, 0, 0);
        }
    }
    __syncthreads();   // all waves done reading W-hi before scratch reuse
    unsigned short* wsm = ldsw + wave * 32 * 136;
#pragma unroll
    for (int rg = 0; rg < 4; rg++) {
        float s0 = dvs[wave * 32 + quad * 4 + rg];
        float s1 = dvs[wave * 32 + 16 + quad * 4 + rg];
#pragma unroll
        for (int nt = 0; nt < 8; nt++) {
            wsm[(quad * 4 + rg) * 136 + nt * 16 + m] = f2bf(acc0[nt][rg] * s0);
            wsm[(16 + quad * 4 + rg) * 136 + nt * 16 + m] = f2bf(acc1[nt][rg] * s1);
        }
    }
    __syncthreads();
#pragma unroll
    for (int i = 0; i < 8; i++) {
        int rl = i * 4 + quad;
        int grow = rowBase + rl;
        if (grow < M) {
            short8 v = *(const short8*)(wsm + rl * 136 + m * 8);
            *(short8*)(ybf + (size_t)grow * 128 + m * 8) = v;
        }
    }
}

// ---------------- fused launch: block b = bsort(b) then gemm1(b) ----------------

__global__ __launch_bounds__(256) void k_fuse(
    const unsigned* __restrict__ bpack, const int* __restrict__ bcnt,
    int* __restrict__ rp, float* __restrict__ dinv, int* __restrict__ esrc, int N,
    const float* __restrict__ A, const unsigned short* __restrict__ wfrag,
    unsigned short* __restrict__ ybf, int M) {
    __shared__ __align__(16) char smem[4 * 32 * 136 * 2];
    __shared__ float dvs[128];
    int b = blockIdx.x;
    bsort_body(smem, b, bpack, bcnt, rp, dinv, esrc, N, dvs);
    __syncthreads();
    gemm_f32_body(smem, b, A, wfrag, dvs, ybf, M);
}

// ---------------- fused agg1 + gemm2 (32-node tile, minimal LDS) — R8/R11 proven ----------------
// R12 lesson: 64-node tile halved block count + doubled phase-A chain ->
// occupancy 64->34%, gather BW 2.86->1.89 TB/s. 32-node is the sweet spot.

__global__ __launch_bounds__(256) void k_aggemm2(
    const unsigned short* __restrict__ y, const float* __restrict__ dinv,
    const int* __restrict__ rp, const int* __restrict__ esrc,
    const float* __restrict__ bias, const unsigned short* __restrict__ wfrag,
    unsigned short* __restrict__ ybf, int N) {
    __shared__ unsigned h1[32 * 68];     // [32 rows][64 u32 + 4 pad] = 8704 B
    int tid = threadIdx.x, wave = tid >> 6, lane = tid & 63;
    int slab = blockIdx.x * 32;
    const unsigned* y2 = (const unsigned*)y;
    float2 bv = ((const float2*)bias)[lane];

    // ---- Phase A: aggregate (proven k_agg inner loop; H1 -> LDS) ----
    for (int ni = 0; ni < 8; ni++) {
        int lr = wave * 8 + ni;
        int node = slab + lr;
        unsigned packed = 0;
        if (node < N) {
            unsigned vs = y2[(size_t)node * 64 + lane];       // self loop
            float a0 = bf2f(vs & 0xFFFF), a1 = bf2f(vs >> 16);
            int beg = rp[node], end = rp[node + 1];
            int j = beg;
            while (j < end) {
                int idxv = (j + lane < end) ? esrc[j + lane] : 0;
                int cnt = end - j; if (cnt > 64) cnt = 64;
                int i = 0;
                for (; i + 4 <= cnt; i += 4) {
                    int s0 = __shfl(idxv, i + 0);
                    int s1 = __shfl(idxv, i + 1);
                    int s2 = __shfl(idxv, i + 2);
                    int s3 = __shfl(idxv, i + 3);
                    unsigned v0 = y2[(size_t)s0 * 64 + lane];
                    unsigned v1 = y2[(size_t)s1 * 64 + lane];
                    unsigned v2 = y2[(size_t)s2 * 64 + lane];
                    unsigned v3 = y2[(size_t)s3 * 64 + lane];
                    a0 += bf2f(v0 & 0xFFFF); a1 += bf2f(v0 >> 16);
                    a0 += bf2f(v1 & 0xFFFF); a1 += bf2f(v1 >> 16);
                    a0 += bf2f(v2 & 0xFFFF); a1 += bf2f(v2 >> 16);
                    a0 += bf2f(v3 & 0xFFFF); a1 += bf2f(v3 >> 16);
                }
                for (; i < cnt; i++) {
                    int s = __shfl(idxv, i);
                    unsigned v = y2[(size_t)s * 64 + lane];
                    a0 += bf2f(v & 0xFFFF); a1 += bf2f(v >> 16);
                }
                j += cnt;
            }
            float s = dinv[node];
            float o0 = fmaxf(s * a0 + bv.x, 0.f);             // relu (conv1)
            float o1 = fmaxf(s * a1 + bv.y, 0.f);
            packed = (unsigned)f2bf(o0) | ((unsigned)f2bf(o1) << 16);
        }
        h1[lr * 68 + lane] = packed;
    }
    __syncthreads();

    // ---- Phase B: gemm2, 32x128 tile; wave w -> col tiles {2w, 2w+1} ----
    const unsigned short* h1us = (const unsigned short*)h1;   // row stride 136 ushort
    int m = lane & 15, quad = lane >> 4;
    f32x4 acc0[2], acc1[2];
#pragma unroll
    for (int i = 0; i < 2; i++) { acc0[i] = (f32x4){0,0,0,0}; acc1[i] = (f32x4){0,0,0,0}; }
    const unsigned short* wlo = wfrag + 16384;
#pragma unroll
    for (int kit = 0; kit < 4; kit++) {
        short8 ah0 = *(const short8*)(h1us + m * 136 + kit * 32 + quad * 8);
        short8 ah1 = *(const short8*)(h1us + (16 + m) * 136 + kit * 32 + quad * 8);
#pragma unroll
        for (int ct = 0; ct < 2; ct++) {
            int idx = kit * 4096 + lane * 8 + (wave * 2 + ct) * 512;
            short8 bhi = *(const short8*)(wfrag + idx);   // from L2 (64KB hot)
            short8 blo = *(const short8*)(wlo + idx);
            acc0[ct] = __builtin_amdgcn_mfma_f32_16x16x32_bf16(ah0, bhi, acc0[ct], 0, 0, 0);
            acc0[ct] = __builtin_amdgcn_mfma_f32_16x16x32_bf16(ah0, blo, acc0[ct], 0, 0, 0);
            acc1[ct] = __builtin_amdgcn_mfma_f32_16x16x32_bf16(ah1, bhi, acc1[ct], 0, 0, 0);
            acc1[ct] = __builtin_amdgcn_mfma_f32_16x16x32_bf16(ah1, blo, acc1[ct], 0, 0, 0);
        }
    }
    float dv0 = (slab + m < N) ? dinv[slab + m] : 0.f;
    float dv1 = (slab + 16 + m < N) ? dinv[slab + 16 + m] : 0.f;
    __syncthreads();   // ALL waves done reading h1 before scratch reuse
    unsigned short* wsm = (unsigned short*)h1;
#pragma unroll
    for (int rg = 0; rg < 4; rg++) {
        float s0 = __shfl(dv0, quad * 4 + rg);
        float s1 = __shfl(dv1, quad * 4 + rg);
#pragma unroll
        for (int ct = 0; ct < 2; ct++) {
            int colb = (wave * 2 + ct) * 16 + m;
            wsm[(quad * 4 + rg) * 136 + colb] = f2bf(acc0[ct][rg] * s0);
            wsm[(16 + quad * 4 + rg) * 136 + colb] = f2bf(acc1[ct][rg] * s1);
        }
    }
    __syncthreads();
#pragma unroll
    for (int pass = 0; pass < 2; pass++) {
        int flat = pass * 256 + tid;
        int rl = flat >> 4, c8 = flat & 15;
        int grow = slab + rl;
        if (grow < N) {
            short8 v = *(const short8*)(wsm + rl * 136 + c8 * 8);
            *(short8*)(ybf + (size_t)grow * 128 + c8 * 8) = v;
        }
    }
}

// ---------------- CSR aggregation (PROVEN R0/R3 form, row-major) ----------------

__global__ __launch_bounds__(256) void k_agg(
    const unsigned short* __restrict__ y, const float* __restrict__ dinv,
    const int* __restrict__ rp, const int* __restrict__ esrc,
    const float* __restrict__ bias, unsigned* __restrict__ out, int relu, int N) {
    int wave = threadIdx.x >> 6;
    int lane = threadIdx.x & 63;
    int node = blockIdx.x * 4 + wave;
    if (node >= N) return;
    const unsigned* y2 = (const unsigned*)y;   // 2 bf16 per u32, row stride 64
    unsigned vs = y2[(size_t)node * 64 + lane];       // self loop
    float a0 = bf2f(vs & 0xFFFF), a1 = bf2f(vs >> 16);
    int beg = rp[node], end = rp[node + 1];
    int j = beg;
    while (j < end) {
        int idxv = (j + lane < end) ? esrc[j + lane] : 0;
        int cnt = end - j; if (cnt > 64) cnt = 64;
        int i = 0;
        for (; i + 4 <= cnt; i += 4) {
            int s0 = __shfl(idxv, i + 0);
            int s1 = __shfl(idxv, i + 1);
            int s2 = __shfl(idxv, i + 2);
            int s3 = __shfl(idxv, i + 3);
            unsigned v0 = y2[(size_t)s0 * 64 + lane];
            unsigned v1 = y2[(size_t)s1 * 64 + lane];
            unsigned v2 = y2[(size_t)s2 * 64 + lane];
            unsigned v3 = y2[(size_t)s3 * 64 + lane];
            a0 += bf2f(v0 & 0xFFFF); a1 += bf2f(v0 >> 16);
            a0 += bf2f(v1 & 0xFFFF); a1 += bf2f(v1 >> 16);
            a0 += bf2f(v2 & 0xFFFF); a1 += bf2f(v2 >> 16);
            a0 += bf2f(v3 & 0xFFFF); a1 += bf2f(v3 >> 16);
        }
        for (; i < cnt; i++) {
            int s = __shfl(idxv, i);
            unsigned v = y2[(size_t)s * 64 + lane];
            a0 += bf2f(v & 0xFFFF); a1 += bf2f(v >> 16);
        }
        j += cnt;
    }
    float s = dinv[node];
    float2 bv = ((const float2*)bias)[lane];
    float o0 = s * a0 + bv.x;
    float o1 = s * a1 + bv.y;
    if (relu) { o0 = fmaxf(o0, 0.f); o1 = fmaxf(o1, 0.f); }
    out[(size_t)node * 64 + lane] = (unsigned)f2bf(o0) | ((unsigned)f2bf(o1) << 16);
}

// ---------------- fused mean-pool + classifier head (proven) ----------------

__global__ __launch_bounds__(256) void k_poolhead(
    const unsigned* __restrict__ h2, const int* __restrict__ batch,
    const float* __restrict__ Wc, const float* __restrict__ bc,
    float* __restrict__ out, int n) {
    __shared__ float2 red[4][64];
    __shared__ float grow[DIM];
    int gid = blockIdx.x;
    int tid = threadIdx.x, wave = tid >> 6, lane = tid & 63;
    int lo = 0, hi = n;
    while (lo < hi) { int mid = (lo + hi) >> 1; if (batch[mid] < gid) lo = mid + 1; else hi = mid; }
    int start = lo;
    hi = n;
    while (lo < hi) { int mid = (lo + hi) >> 1; if (batch[mid] < gid + 1) lo = mid + 1; else hi = mid; }
    int end = lo;
    float a0 = 0.f, a1 = 0.f;
    for (int r = start + wave; r < end; r += 4) {
        unsigned v = h2[(size_t)r * 64 + lane];
        a0 += bf2f(v & 0xFFFF); a1 += bf2f(v >> 16);
    }
    red[wave][lane] = make_float2(a0, a1);
    __syncthreads();
    if (tid < 64) {
        float2 s = red[0][tid];
        s.x += red[1][tid].x; s.y += red[1][tid].y;
        s.x += red[2][tid].x; s.y += red[2][tid].y;
        s.x += red[3][tid].x; s.y += red[3][tid].y;
        int cnt = end - start;
        float inv = 1.f / (float)(cnt > 0 ? cnt : 1);
        grow[tid * 2] = s.x * inv;
        grow[tid * 2 + 1] = s.y * inv;
    }
    __syncthreads();
    if (tid < NCLS) {
        float acc = bc[tid];
#pragma unroll 16
        for (int k = 0; k < DIM; k++) acc += grow[k] * Wc[k * NCLS + tid];
        out[gid * NCLS + tid] = acc;
    }
}

extern "C" void kernel_launch(void* const* d_in, const int* in_sizes, int n_in,
                              void* d_out, int out_size, void* d_ws, size_t ws_size,
                              hipStream_t stream) {
    const float* x    = (const float*)d_in[0];
    const int*   ei   = (const int*)d_in[1];
    const int*   batch= (const int*)d_in[2];
    const float* W1   = (const float*)d_in[3];
    const float* b1   = (const float*)d_in[4];
    const float* W2   = (const float*)d_in[5];
    const float* b2   = (const float*)d_in[6];
    const float* Wc   = (const float*)d_in[7];
    const float* bc   = (const float*)d_in[8];
    float* out = (float*)d_out;
    const int N = N_NODES, E = N_EDGES;
    const int* src = ei;
    const int* dst = ei + E;

    char* ws = (char*)d_ws;
    size_t off = 0;
    auto carve = [&](size_t bytes) -> void* {
        void* p = ws + off;
        off = (off + bytes + 255) & ~(size_t)255;
        return p;
    };
    int*      rp    = (int*)     carve((size_t)(N + 1) * 4);
    float*    dinv  = (float*)   carve((size_t)N * 4);
    int*      bcnt  = (int*)     carve(NBKT * 4);
    unsigned* bpack = (unsigned*)carve((size_t)NBKT * BCAP * 4);
    int*      esrc  = (int*)     carve((size_t)E * 4);
    unsigned short* wf1 = (unsigned short*)carve(2 * 16384 * 2);
    unsigned short* wf2 = (unsigned short*)carve(2 * 16384 * 2);
    unsigned short* bufY = (unsigned short*)carve((size_t)N * DIM * 2);
    unsigned short* bufH = (unsigned short*)carve((size_t)N * DIM * 2);
    (void)ws_size; (void)n_in; (void)in_sizes; (void)out_size;

    const int nbBkt = (E + 4095) / 4096;        // 391 bucket blocks

    // bcnt zero: stream-ordered memset, complete before k_bucket starts
    hipMemsetAsync(bcnt, 0, NBKT * sizeof(int), stream);
    // merged: 32 W-prep blocks at grid HEAD (finish fast) + 391 bucket blocks
    hipLaunchKernelGGL(k_bucket, dim3(32 + nbBkt), dim3(1024), 0, stream,
                       src, dst, bcnt, bpack, E, W1, W2, wf1, wf2);
    // fused: block b does bsort(bucket b) then gemm1(rows of bucket b) -> Y1 (pre-scaled)
    hipLaunchKernelGGL(k_fuse, dim3(NBKT), dim3(256), 0, stream,
                       bpack, bcnt, rp, dinv, esrc, N, x, wf1, bufY, N);
    // fused: agg1 (H1 in 8.7KB LDS, 32-node tile) + gemm2 -> Y2 (pre-scaled)
    hipLaunchKernelGGL(k_aggemm2, dim3((N + 31) / 32), dim3(256), 0, stream,
                       bufY, dinv, rp, esrc, b1, wf2, bufH, N);
    // conv2 aggregate: H2 = dinv*agg(Y2) + b2
    hipLaunchKernelGGL(k_agg, dim3((N + 3) / 4), dim3(256), 0, stream, bufH, dinv, rp, esrc, b2, (unsigned*)bufY, 0, N);
    // fused pool + head
    hipLaunchKernelGGL(k_poolhead, dim3(N_GRAPHS), dim3(256), 0, stream, (const unsigned*)bufY, batch, Wc, bc, out, N);
}